// Round 7
// baseline (44.373 us; speedup 1.0000x reference)
//
#include <hip/hip_runtime.h>
#include <math.h>

#define NQ 6
#define NLAYERS 2
#define ROW_D 512

typedef short short8 __attribute__((ext_vector_type(8)));   // 8 bf16 in 4 VGPRs
typedef float f32x4 __attribute__((ext_vector_type(4)));

__device__ __forceinline__ ushort f2bf(float f) {           // f32 -> bf16 (RNE)
    unsigned u = __float_as_uint(f);
    return (ushort)((u + 0x7fffu + ((u >> 16) & 1u)) >> 16);
}
__device__ __forceinline__ float bf2f(ushort h) {
    return __uint_as_float((unsigned)h << 16);
}
__device__ __forceinline__ float merge_red(float u, float v, int m, int lane) {
    float send = (lane & m) ? u : v;
    float recv = __shfl_xor(send, m, 64);
    return ((lane & m) ? v : u) + recv;
}

// ws layout: ushort[0,4096) U'_re, [4096,8192) U'_im,
// ushort[8192,16384) W_packed 16x512 (rows 0..5 = W_hi, 8..13 = W_lo, else 0)
// byte offset 32768+: z-tiles, float4[chunk][64]  (4 MB for B=65536)
__global__ __launch_bounds__(256) void gen_tables(
    const float* __restrict__ weights, const float* __restrict__ W,
    ushort* __restrict__ ws)
{
    const int tid = threadIdx.x;
    {
        const int base = (blockIdx.x * 256 + tid) * 2;
        #pragma unroll
        for (int e = 0; e < 2; ++e) {
            const int i = base + e;
            const int n = i >> 9, k = i & 511;
            ushort v = 0;
            if (n < NQ) {
                v = f2bf(W[(n << 9) | k]);
            } else if (n >= 8 && n < 8 + NQ) {
                const float w = W[((n - 8) << 9) | k];
                v = f2bf(w - bf2f(f2bf(w)));
            }
            ws[8192 + i] = v;
        }
    }

    __shared__ __align__(16) float gmat[NLAYERS * NQ * 8];
    if (tid < NLAYERS * NQ) {
        float phi = weights[tid * 3 + 0];
        float th  = weights[tid * 3 + 1];
        float om  = weights[tid * 3 + 2];
        float st, ct, sA, cA, sB, cB;
        __sincosf(0.5f * th, &st, &ct);
        __sincosf(0.5f * (phi + om), &sA, &cA);
        __sincosf(0.5f * (phi - om), &sB, &cB);
        float* g = &gmat[tid * 8];
        g[0] =  cA * ct;  g[1] = -sA * ct;   // u00
        g[2] = -cB * st;  g[3] = -sB * st;   // u01
        g[4] =  cA * ct;  g[5] =  sA * ct;   // u11
        g[6] =  cB * st;  g[7] = -sB * st;   // u10
    }
    __syncthreads();

    const int lane = tid & 63;
    const int wave = tid >> 6;
    const int jj = blockIdx.x * 4 + wave;

    int srcA = lane;
    #pragma unroll
    for (int q = NQ - 1; q >= 0; --q) {
        const int t = (q + 1) % NQ;
        srcA ^= ((srcA >> (5 - q)) & 1) << (5 - t);
    }
    int srcB = lane;
    #pragma unroll
    for (int q = NQ - 1; q >= 0; --q) {
        const int t = (q + 2) % NQ;
        srcB ^= ((srcB >> (5 - q)) & 1) << (5 - t);
    }
    const int adA = srcA << 2, adB = srcB << 2;

    float sr = (lane == jj) ? 1.f : 0.f;
    float si = 0.f;
    #pragma unroll
    for (int l = 0; l < NLAYERS; ++l) {
        #pragma unroll
        for (int q = 0; q < NQ; ++q) {
            const int bp = 5 - q, m = 1 << bp;
            const int bit = (lane >> bp) & 1;
            const float4 g = *reinterpret_cast<const float4*>(
                &gmat[((l * NQ + q) << 3) + (bit << 2)]);
            float pr = __shfl_xor(sr, m, 64);
            float pi = __shfl_xor(si, m, 64);
            float nr = g.x * sr - g.y * si + g.z * pr - g.w * pi;
            float ni = g.x * si + g.y * sr + g.z * pi + g.w * pr;
            sr = nr; si = ni;
        }
        const int ad = (l == 0) ? adA : adB;
        sr = __int_as_float(__builtin_amdgcn_ds_bpermute(ad, __float_as_int(sr)));
        si = __int_as_float(__builtin_amdgcn_ds_bpermute(ad, __float_as_int(si)));
    }

    const int pc = __popc(jj) & 3;
    float r2, i2;
    if      (pc == 1) { r2 =  si; i2 = -sr; }
    else if (pc == 2) { r2 = -sr; i2 = -si; }
    else if (pc == 3) { r2 = -si; i2 =  sr; }
    else              { r2 =  sr; i2 =  si; }
    ws[lane * 64 + jj]        = f2bf(r2);
    ws[4096 + lane * 64 + jj] = f2bf(i2);
}

// --------- Kernel A: pure streaming GEMV. 1 chunk (16 rows) per wave. ------
// Tail per chunk = ONE dwordx4 store of the raw MFMA C-tile.
__global__ __launch_bounds__(256, 4) void zgemv(
    const float* __restrict__ x, const ushort* __restrict__ ws,
    float4* __restrict__ zout, int B)
{
    __shared__ short8 Wlds[16][64];        // 16 KB W packed hi/lo, swizzled
    const int tid = threadIdx.x;
    const short8* mg = reinterpret_cast<const short8*>(ws);
    #pragma unroll
    for (int i = 0; i < 4; ++i) {
        const int idx = tid + i * 256;
        short8 v = mg[1024 + idx];
        const int n = idx >> 6, c = idx & 63;
        Wlds[n][c ^ (n & 7)] = v;
    }
    __syncthreads();

    const int lane = tid & 63;
    const int wave = tid >> 6;
    const int g  = lane >> 4;
    const int l4 = lane & 15;
    const int swz = l4 & 7;

    const int chunk = blockIdx.x * 4 + wave;      // 16 rows per chunk
    const float* xrow = x + (size_t)chunk * 16 * ROW_D + (size_t)l4 * ROW_D + g * 8;

    f32x4 zacc = {0.f, 0.f, 0.f, 0.f};
    #pragma unroll 8
    for (int kt = 0; kt < 16; ++kt) {
        const float4 xa = *reinterpret_cast<const float4*>(xrow + kt * 32);
        const float4 xb = *reinterpret_cast<const float4*>(xrow + kt * 32 + 4);
        short8 af;
        af[0] = (short)f2bf(xa.x); af[1] = (short)f2bf(xa.y);
        af[2] = (short)f2bf(xa.z); af[3] = (short)f2bf(xa.w);
        af[4] = (short)f2bf(xb.x); af[5] = (short)f2bf(xb.y);
        af[6] = (short)f2bf(xb.z); af[7] = (short)f2bf(xb.w);
        const short8 bw = Wlds[l4][(kt * 4 + g) ^ swz];
        zacc = __builtin_amdgcn_mfma_f32_16x16x32_bf16(af, bw, zacc, 0, 0, 0);
    }
    zout[(size_t)chunk * 64 + lane] = *reinterpret_cast<float4*>(&zacc);
}

// --------- Kernel B: z-tiles -> norm -> w -> S-GEMM -> expvals -------------
__global__ __launch_bounds__(256, 4) void qtail(
    const float4* __restrict__ zin, const float* __restrict__ bvec,
    const ushort* __restrict__ ws, float* __restrict__ out, int B)
{
    __shared__ float2 trans[4][144];       // 4.5 KB sincos transpose
    const int tid = threadIdx.x;
    const int lane = tid & 63;
    const int wave = tid >> 6;
    const int g  = lane >> 4;
    const int l4 = lane & 15;
    const short8* mg = reinterpret_cast<const short8*>(ws);

    const int chunk = blockIdx.x * 4 + wave;
    const int rowbase = chunk * 16;
    const float4 zt = zin[(size_t)chunk * 64 + lane];
    const f32x4 zacc = {zt.x, zt.y, zt.z, zt.w};

    const float bn = (l4 < NQ) ? bvec[l4] : 0.f;
    #pragma unroll
    for (int reg = 0; reg < 4; ++reg) {
        const float zlo = __shfl_xor(zacc[reg], 8, 64);
        const float zv = zacc[reg] + zlo + bn;    // valid where l4 < 6
        float s2 = (l4 < NQ) ? zv * zv : 0.f;
        s2 += __shfl_xor(s2, 1, 64);
        s2 += __shfl_xor(s2, 2, 64);
        s2 += __shfl_xor(s2, 4, 64);
        s2 += __shfl_xor(s2, 8, 64);
        const float ang = 0.5f * zv * rsqrtf(s2);
        float sv, cv;
        __sincosf(ang, &sv, &cv);
        if (l4 < NQ)
            trans[wave][(g * 4 + reg) * 9 + l4] = make_float2(cv, sv);
    }

    float cq[NQ], sq[NQ];
    #pragma unroll
    for (int q = 0; q < NQ; ++q) {
        const float2 cs = trans[wave][l4 * 9 + q];
        cq[q] = cs.x; sq[q] = cs.y;
    }
    float m45[4];
    m45[0] = cq[4] * cq[5]; m45[1] = cq[4] * sq[5];
    m45[2] = sq[4] * cq[5]; m45[3] = sq[4] * sq[5];
    float pl[8];
    #pragma unroll
    for (int j = 0; j < 8; ++j)
        pl[j] = ((j & 4) ? sq[3] : cq[3]) * m45[j & 3];
    const float t12 = ((g & 2) ? sq[1] : cq[1]) * ((g & 1) ? sq[2] : cq[2]);
    const float ph0 = cq[0] * t12;
    const float ph1 = sq[0] * t12;
    short8 a0, a1;
    #pragma unroll
    for (int j = 0; j < 8; ++j) {
        a0[j] = (short)f2bf(ph0 * pl[j]);
        a1[j] = (short)f2bf(ph1 * pl[j]);
    }

    // S-GEMM: U' B-frags straight from global (L1/L2-hot 16 KB)
    f32x4 cre[4] = {}, cim[4] = {};
    #pragma unroll
    for (int nt = 0; nt < 4; ++nt) {
        const int brow = nt * 16 + l4;
        const short8 br0 = mg[brow * 8 + g];
        const short8 br1 = mg[brow * 8 + 4 + g];
        const short8 bi0 = mg[512 + brow * 8 + g];
        const short8 bi1 = mg[512 + brow * 8 + 4 + g];
        cre[nt] = __builtin_amdgcn_mfma_f32_16x16x32_bf16(a0, br0, cre[nt], 0, 0, 0);
        cre[nt] = __builtin_amdgcn_mfma_f32_16x16x32_bf16(a1, br1, cre[nt], 0, 0, 0);
        cim[nt] = __builtin_amdgcn_mfma_f32_16x16x32_bf16(a0, bi0, cim[nt], 0, 0, 0);
        cim[nt] = __builtin_amdgcn_mfma_f32_16x16x32_bf16(a1, bi1, cim[nt], 0, 0, 0);
    }

    const int col = l4;
    #pragma unroll
    for (int reg = 0; reg < 4; ++reg) {
        const float p0 = cre[0][reg] * cre[0][reg] + cim[0][reg] * cim[0][reg];
        const float p1 = cre[1][reg] * cre[1][reg] + cim[1][reg] * cim[1][reg];
        const float p2 = cre[2][reg] * cre[2][reg] + cim[2][reg] * cim[2][reg];
        const float p3 = cre[3][reg] * cre[3][reg] + cim[3][reg] * cim[3][reg];
        float t  = (p0 + p1) + (p2 + p3);
        float y0 = (p0 + p1) - (p2 + p3);        // q0
        float y1 = (p0 + p2) - (p1 + p3);        // q1
        #pragma unroll
        for (int m = 1; m <= 8; m <<= 1) {
            float rcv = __shfl_xor(t, m, 64);
            t = (lane & m) ? (rcv - t) : (t + rcv);
        }
        float y = merge_red(y0, y1, 1, lane);
        y += __shfl_xor(y, 2, 64);
        y += __shfl_xor(y, 4, 64);
        y += __shfl_xor(y, 8, 64);
        const size_t orow = (size_t)(rowbase + g * 4 + reg) * 6;
        if      (col == 0) { out[orow + 0] = y; }
        else if (col == 1) { out[orow + 1] = y; out[orow + 5] = t; }
        else if (col == 2) { out[orow + 4] = t; }
        else if (col == 4) { out[orow + 3] = t; }
        else if (col == 8) { out[orow + 2] = t; }
    }
}

extern "C" void kernel_launch(void* const* d_in, const int* in_sizes, int n_in,
                              void* d_out, int out_size, void* d_ws, size_t ws_size,
                              hipStream_t stream) {
    const float* x  = (const float*)d_in[0];
    const float* W  = (const float*)d_in[1];
    const float* bv = (const float*)d_in[2];
    const float* wt = (const float*)d_in[3];
    float* out = (float*)d_out;
    ushort* ws = (ushort*)d_ws;                         // 32 KB tables
    float4* zt = (float4*)((char*)d_ws + 32768);        // 4 MB z-tiles
    const int B = in_sizes[0] / ROW_D;
    const int chunks = B / 16;
    gen_tables<<<16, 256, 0, stream>>>(wt, W, ws);
    zgemv<<<chunks / 4, 256, 0, stream>>>(x, ws, zt, B);
    qtail<<<chunks / 4, 256, 0, stream>>>(zt, bv, ws, out, B);
}

// Round 8
// 34.254 us; speedup vs baseline: 1.2954x; 1.2954x over previous
//
#include <hip/hip_runtime.h>
#include <math.h>

#define NQ 6
#define NLAYERS 2
#define ROW_D 512

typedef short short8 __attribute__((ext_vector_type(8)));   // 8 bf16 in 4 VGPRs
typedef float f32x4 __attribute__((ext_vector_type(4)));

__device__ __forceinline__ ushort f2bf(float f) {           // f32 -> bf16 (RNE)
    unsigned u = __float_as_uint(f);
    return (ushort)((u + 0x7fffu + ((u >> 16) & 1u)) >> 16);
}
__device__ __forceinline__ float bf2f(ushort h) {
    return __uint_as_float((unsigned)h << 16);
}
// packed f32x2 -> bf16x2 (RNE), single VALU op
__device__ __forceinline__ unsigned cvt2bf(float lo, float hi) {
    unsigned r;
    asm("v_cvt_pk_bf16_f32 %0, %1, %2" : "=v"(r) : "v"(lo), "v"(hi));
    return r;
}
__device__ __forceinline__ float merge_red(float u, float v, int m, int lane) {
    float send = (lane & m) ? u : v;
    float recv = __shfl_xor(send, m, 64);
    return ((lane & m) ? v : u) + recv;
}

// ws layout (ushort): [0,4096) U'_re, [4096,8192) U'_im,
// [8192,16384) W_packed 16x512 (rows 0..5 = W_hi, 8..13 = W_lo, else 0),
// stored with the z-GEMM k-slot permutation applied within each 32-float window.
__global__ __launch_bounds__(256) void gen_tables(
    const float* __restrict__ weights, const float* __restrict__ W,
    ushort* __restrict__ ws)
{
    const int tid = threadIdx.x;
    {
        const int base = (blockIdx.x * 256 + tid) * 2;
        #pragma unroll
        for (int e = 0; e < 2; ++e) {
            const int i = base + e;
            const int n = i >> 9, k = i & 511;
            // k-slot permutation: slot (g = bits4:3, e2 = bits2:0) of window w
            // sources x/W float  w*32 + (e2<4 ? 4g+e2 : 16+4g+(e2-4))
            const int w = k >> 5, g = (k >> 3) & 3, e2 = k & 7;
            const int ksrc = w * 32 + ((e2 < 4) ? (4 * g + e2) : (16 + 4 * g + e2 - 4));
            ushort v = 0;
            if (n < NQ) {
                v = f2bf(W[(n << 9) | ksrc]);
            } else if (n >= 8 && n < 8 + NQ) {
                const float wv = W[((n - 8) << 9) | ksrc];
                v = f2bf(wv - bf2f(f2bf(wv)));
            }
            ws[8192 + i] = v;
        }
    }

    __shared__ __align__(16) float gmat[NLAYERS * NQ * 8];
    if (tid < NLAYERS * NQ) {
        float phi = weights[tid * 3 + 0];
        float th  = weights[tid * 3 + 1];
        float om  = weights[tid * 3 + 2];
        float st, ct, sA, cA, sB, cB;
        __sincosf(0.5f * th, &st, &ct);
        __sincosf(0.5f * (phi + om), &sA, &cA);
        __sincosf(0.5f * (phi - om), &sB, &cB);
        float* g = &gmat[tid * 8];
        g[0] =  cA * ct;  g[1] = -sA * ct;   // u00
        g[2] = -cB * st;  g[3] = -sB * st;   // u01
        g[4] =  cA * ct;  g[5] =  sA * ct;   // u11
        g[6] =  cB * st;  g[7] = -sB * st;   // u10
    }
    __syncthreads();

    const int lane = tid & 63;
    const int wave = tid >> 6;
    const int jj = blockIdx.x * 4 + wave;

    int srcA = lane;
    #pragma unroll
    for (int q = NQ - 1; q >= 0; --q) {
        const int t = (q + 1) % NQ;
        srcA ^= ((srcA >> (5 - q)) & 1) << (5 - t);
    }
    int srcB = lane;
    #pragma unroll
    for (int q = NQ - 1; q >= 0; --q) {
        const int t = (q + 2) % NQ;
        srcB ^= ((srcB >> (5 - q)) & 1) << (5 - t);
    }
    const int adA = srcA << 2, adB = srcB << 2;

    float sr = (lane == jj) ? 1.f : 0.f;
    float si = 0.f;
    #pragma unroll
    for (int l = 0; l < NLAYERS; ++l) {
        #pragma unroll
        for (int q = 0; q < NQ; ++q) {
            const int bp = 5 - q, m = 1 << bp;
            const int bit = (lane >> bp) & 1;
            const float4 g = *reinterpret_cast<const float4*>(
                &gmat[((l * NQ + q) << 3) + (bit << 2)]);
            float pr = __shfl_xor(sr, m, 64);
            float pi = __shfl_xor(si, m, 64);
            float nr = g.x * sr - g.y * si + g.z * pr - g.w * pi;
            float ni = g.x * si + g.y * sr + g.z * pi + g.w * pr;
            sr = nr; si = ni;
        }
        const int ad = (l == 0) ? adA : adB;
        sr = __int_as_float(__builtin_amdgcn_ds_bpermute(ad, __float_as_int(sr)));
        si = __int_as_float(__builtin_amdgcn_ds_bpermute(ad, __float_as_int(si)));
    }

    const int pc = __popc(jj) & 3;
    float r2, i2;
    if      (pc == 1) { r2 =  si; i2 = -sr; }
    else if (pc == 2) { r2 = -sr; i2 = -si; }
    else if (pc == 3) { r2 = -si; i2 =  sr; }
    else              { r2 =  sr; i2 =  si; }
    ws[lane * 64 + jj]        = f2bf(r2);
    ws[4096 + lane * 64 + jj] = f2bf(i2);
}

// ---------------- main kernel: all-MFMA pipeline ---------------------------
__global__ __launch_bounds__(256, 4) void qmain(
    const float* __restrict__ x, const float* __restrict__ bvec,
    const ushort* __restrict__ ws, float* __restrict__ out, int B)
{
    __shared__ short8 Mlds[2][64][8];      // 16 KB  U' re/im, chunk-swizzled
    __shared__ short8 Wlds[16][64];        // 16 KB  W packed hi/lo, swizzled
    __shared__ float2 trans[4][144];       // 4.5 KB sincos transpose
    const int tid = threadIdx.x;

    const short8* mg = reinterpret_cast<const short8*>(ws);
    #pragma unroll
    for (int i = 0; i < 4; ++i) {
        const int idx = tid + i * 256;                // U': 1024 chunks
        short8 v = mg[idx];
        const int mat = idx >> 9, row = (idx >> 3) & 63, c = idx & 7;
        Mlds[mat][row][c ^ (row & 7)] = v;
    }
    #pragma unroll
    for (int i = 0; i < 4; ++i) {
        const int idx = tid + i * 256;                // W: 1024 chunks
        short8 v = mg[1024 + idx];
        const int n = idx >> 6, c = idx & 63;
        Wlds[n][c ^ (n & 7)] = v;
    }
    __syncthreads();

    const int lane = tid & 63;
    const int wave = tid >> 6;
    const int g  = lane >> 4;      // k-group
    const int l4 = lane & 15;      // A-frag row / B-frag col
    const int swz = l4 & 7;
    const int rowbase = blockIdx.x * 64 + wave * 16;

    // ---- z-GEMM: full-sector loads. xa covers bytes [16g,16g+16) of the
    // row's kt-window (4 g-lanes -> one full 64B sector); xb covers
    // [64+16g, ...). k-slot permutation matches gen_tables' W packing. ----
    f32x4 zacc = {0.f, 0.f, 0.f, 0.f};
    const float* xrow = x + (size_t)(rowbase + l4) * ROW_D + g * 4;
    #pragma unroll 8
    for (int kt = 0; kt < 16; ++kt) {
        const float4 xa = *reinterpret_cast<const float4*>(xrow + kt * 32);
        const float4 xb = *reinterpret_cast<const float4*>(xrow + kt * 32 + 16);
        uint4 u;
        u.x = cvt2bf(xa.x, xa.y);
        u.y = cvt2bf(xa.z, xa.w);
        u.z = cvt2bf(xb.x, xb.y);
        u.w = cvt2bf(xb.z, xb.w);
        const short8 af = __builtin_bit_cast(short8, u);
        const short8 bw = Wlds[l4][(kt * 4 + g) ^ swz];
        zacc = __builtin_amdgcn_mfma_f32_16x16x32_bf16(af, bw, zacc, 0, 0, 0);
    }

    // ---- z = z_hi + z_lo, bias, norm, sincos, transpose ------------------
    const float bn = (l4 < NQ) ? bvec[l4] : 0.f;
    #pragma unroll
    for (int reg = 0; reg < 4; ++reg) {
        const float zlo = __shfl_xor(zacc[reg], 8, 64);
        const float zv = zacc[reg] + zlo + bn;    // valid where l4 < 6
        float s2 = (l4 < NQ) ? zv * zv : 0.f;
        s2 += __shfl_xor(s2, 1, 64);
        s2 += __shfl_xor(s2, 2, 64);
        s2 += __shfl_xor(s2, 4, 64);
        s2 += __shfl_xor(s2, 8, 64);
        const float ang = 0.5f * zv * rsqrtf(s2);
        float sv, cv;
        __sincosf(ang, &sv, &cv);
        if (l4 < NQ)
            trans[wave][(g * 4 + reg) * 9 + l4] = make_float2(cv, sv);
    }

    // ---- gather this lane's row (m = l4) factors, build w A-frags --------
    float cq[NQ], sq[NQ];
    #pragma unroll
    for (int q = 0; q < NQ; ++q) {
        const float2 cs = trans[wave][l4 * 9 + q];
        cq[q] = cs.x; sq[q] = cs.y;
    }
    float m45[4];
    m45[0] = cq[4] * cq[5]; m45[1] = cq[4] * sq[5];
    m45[2] = sq[4] * cq[5]; m45[3] = sq[4] * sq[5];
    float pl[8];
    #pragma unroll
    for (int j = 0; j < 8; ++j)
        pl[j] = ((j & 4) ? sq[3] : cq[3]) * m45[j & 3];
    const float t12 = ((g & 2) ? sq[1] : cq[1]) * ((g & 1) ? sq[2] : cq[2]);
    const float ph0 = cq[0] * t12;                 // khi = g   (bit q0 = 0)
    const float ph1 = sq[0] * t12;                 // khi = g+4 (bit q0 = 1)
    uint4 ua, ub;
    ua.x = cvt2bf(ph0 * pl[0], ph0 * pl[1]);
    ua.y = cvt2bf(ph0 * pl[2], ph0 * pl[3]);
    ua.z = cvt2bf(ph0 * pl[4], ph0 * pl[5]);
    ua.w = cvt2bf(ph0 * pl[6], ph0 * pl[7]);
    ub.x = cvt2bf(ph1 * pl[0], ph1 * pl[1]);
    ub.y = cvt2bf(ph1 * pl[2], ph1 * pl[3]);
    ub.z = cvt2bf(ph1 * pl[4], ph1 * pl[5]);
    ub.w = cvt2bf(ph1 * pl[6], ph1 * pl[7]);
    const short8 a0 = __builtin_bit_cast(short8, ua);
    const short8 a1 = __builtin_bit_cast(short8, ub);

    // ---- S-GEMM: S = w * U'^T (M=16,N=64,K=64), re & im ------------------
    f32x4 cre[4] = {}, cim[4] = {};
    #pragma unroll
    for (int nt = 0; nt < 4; ++nt) {
        const int brow = nt * 16 + l4;
        const short8 br0 = Mlds[0][brow][(g)     ^ swz];
        const short8 br1 = Mlds[0][brow][(4 + g) ^ swz];
        const short8 bi0 = Mlds[1][brow][(g)     ^ swz];
        const short8 bi1 = Mlds[1][brow][(4 + g) ^ swz];
        cre[nt] = __builtin_amdgcn_mfma_f32_16x16x32_bf16(a0, br0, cre[nt], 0, 0, 0);
        cre[nt] = __builtin_amdgcn_mfma_f32_16x16x32_bf16(a1, br1, cre[nt], 0, 0, 0);
        cim[nt] = __builtin_amdgcn_mfma_f32_16x16x32_bf16(a0, bi0, cim[nt], 0, 0, 0);
        cim[nt] = __builtin_amdgcn_mfma_f32_16x16x32_bf16(a1, bi1, cim[nt], 0, 0, 0);
    }

    // ---- epilogue: probs -> 6 signed sums (WHT over n) -------------------
    const int col = l4;
    #pragma unroll
    for (int reg = 0; reg < 4; ++reg) {
        const float p0 = cre[0][reg] * cre[0][reg] + cim[0][reg] * cim[0][reg];
        const float p1 = cre[1][reg] * cre[1][reg] + cim[1][reg] * cim[1][reg];
        const float p2 = cre[2][reg] * cre[2][reg] + cim[2][reg] * cim[2][reg];
        const float p3 = cre[3][reg] * cre[3][reg] + cim[3][reg] * cim[3][reg];
        float t  = (p0 + p1) + (p2 + p3);        // -> q2..q5 via WHT over col
        float y0 = (p0 + p1) - (p2 + p3);        // q0 (bit5 = nt>>1)
        float y1 = (p0 + p2) - (p1 + p3);        // q1 (bit4 = nt&1)
        #pragma unroll
        for (int m = 1; m <= 8; m <<= 1) {
            float rcv = __shfl_xor(t, m, 64);
            t = (lane & m) ? (rcv - t) : (t + rcv);
        }
        float y = merge_red(y0, y1, 1, lane);
        y += __shfl_xor(y, 2, 64);
        y += __shfl_xor(y, 4, 64);
        y += __shfl_xor(y, 8, 64);
        const size_t orow = (size_t)(rowbase + g * 4 + reg) * 6;
        if      (col == 0) { out[orow + 0] = y; }
        else if (col == 1) { out[orow + 1] = y; out[orow + 5] = t; }
        else if (col == 2) { out[orow + 4] = t; }
        else if (col == 4) { out[orow + 3] = t; }
        else if (col == 8) { out[orow + 2] = t; }
    }
}

extern "C" void kernel_launch(void* const* d_in, const int* in_sizes, int n_in,
                              void* d_out, int out_size, void* d_ws, size_t ws_size,
                              hipStream_t stream) {
    const float* x  = (const float*)d_in[0];
    const float* W  = (const float*)d_in[1];
    const float* bv = (const float*)d_in[2];
    const float* wt = (const float*)d_in[3];
    float* out = (float*)d_out;
    ushort* ws = (ushort*)d_ws;             // 32 KB of tables
    const int B = in_sizes[0] / ROW_D;
    gen_tables<<<16, 256, 0, stream>>>(wt, W, ws);
    qmain<<<B / 64, 256, 0, stream>>>(x, bv, ws, out, B);
}